// Round 1
// baseline (5047.577 us; speedup 1.0000x reference)
//
#include <hip/hip_runtime.h>
#include <math.h>

// Problem constants
#define BB 4
#define HH 512
#define WW 512
#define IMGPIX (HH*WW)        // 262144
#define NPIX (BB*IMGPIX)      // 1048576
#define KSEL 512
#define NPROP (BB*KSEL)       // 2048
#define CUP 64
#define NMS_THR 0.2f

// Workspace layout (bytes)
#define OFF_S32   0                       // double[4096]  = 32768
#define OFF_SUM   32768                   // double
#define OFF_CNT   32776                   // ull
#define OFF_BM    33280                   // float[1048576] = 4 MB
#define OFF_RM    (OFF_BM + 4194304)
#define OFF_KEYS  (OFF_RM + 4194304)      // u64[1048576] = 8 MB
#define OFF_PROPS (OFF_KEYS + 8388608)    // int[4096]

#define LRELU_F(x) ((x) > 0.0f ? (x) : 0.1f*(x))

// ---------------------------------------------------------------------------
// Stage 1: per-pixel patch MLP (f64 for numerical fidelity), 16 px per block
// ---------------------------------------------------------------------------
__global__ __launch_bounds__(256) void patch_k(
    const float* __restrict__ fdown,
    const float* __restrict__ pw1, const float* __restrict__ pb1,
    const float* __restrict__ pw2, const float* __restrict__ pb2,
    const float* __restrict__ pw3, const float* __restrict__ pb3,
    const float* __restrict__ pfcw, const float* __restrict__ pfcb,
    double* __restrict__ s32)
{
  __shared__ double xb[16][256];
  const int t = threadIdx.x;
  const int base_px = blockIdx.x * 16;
#pragma unroll
  for (int p = 0; p < 16; ++p) {
    int px = base_px + p;
    int b = px >> 10, rem = px & 1023;
    xb[p][t] = (double)fdown[(size_t)(b*256 + t)*1024 + rem];
  }
  __syncthreads();
  const float* Ws[3] = {pw1, pw2, pw3};
  const float* Bs[3] = {pb1, pb2, pb3};
  for (int L = 0; L < 3; ++L) {
    double acc[16];
    double bias = (double)Bs[L][t];
#pragma unroll
    for (int p = 0; p < 16; ++p) acc[p] = bias;
    const float* wrow = Ws[L] + t*256;
    for (int c = 0; c < 256; ++c) {
      double wv = (double)wrow[c];
#pragma unroll
      for (int p = 0; p < 16; ++p) acc[p] += wv * xb[p][c];
    }
    __syncthreads();
#pragma unroll
    for (int p = 0; p < 16; ++p)
      xb[p][t] = acc[p] > 0.0 ? acc[p] : 0.1*acc[p];
    __syncthreads();
  }
  if (t < 16) {
    double l0 = (double)pfcb[0], l1 = (double)pfcb[1];
    for (int c = 0; c < 256; ++c) {
      double xv = xb[t][c];
      l0 += (double)pfcw[c]       * xv;
      l1 += (double)pfcw[256 + c] * xv;
    }
    double m  = fmax(l0, l1);
    double e0 = exp(l0 - m), e1 = exp(l1 - m);
    s32[base_px + t] = e1 / (e0 + e1);
  }
}

// Bilinear upsample 32->512 (align_corners=False semantics, edge-clamped),
// matches jax.image.resize('bilinear') for 16x integer upsampling.
__device__ __forceinline__ double upsample_ps(const double* __restrict__ s32,
                                              int b, int oy, int ox)
{
  double sy = (oy + 0.5)*0.0625 - 0.5;
  double sx = (ox + 0.5)*0.0625 - 0.5;
  double fy = floor(sy), fx = floor(sx);
  double wy = sy - fy,   wx = sx - fx;
  int y0 = (int)fy, x0 = (int)fx;
  int y0i = min(max(y0,   0), 31), y1i = min(max(y0+1, 0), 31);
  int x0i = min(max(x0,   0), 31), x1i = min(max(x0+1, 0), 31);
  const double* s = s32 + b*1024;
  double v00 = s[y0i*32+x0i], v01 = s[y0i*32+x1i];
  double v10 = s[y1i*32+x0i], v11 = s[y1i*32+x1i];
  return v00*(1.0-wy)*(1.0-wx) + v01*(1.0-wy)*wx
       + v10*wy*(1.0-wx)       + v11*wy*wx;
}

// ---------------------------------------------------------------------------
// Stage 2a: global bad-pixel sum/count (f64 accumulation)
// ---------------------------------------------------------------------------
__global__ __launch_bounds__(256) void mean_k(
    const float* __restrict__ xhat, const double* __restrict__ s32,
    double* __restrict__ sum, unsigned long long* __restrict__ cnt)
{
  int id = blockIdx.x*256 + threadIdx.x;
  int b = id >> 18, rem = id & (IMGPIX-1);
  int oy = rem >> 9, ox = rem & 511;
  double ps = upsample_ps(s32, b, oy, ox);
  bool bad = ps < 0.5;
  double v = bad ? (double)xhat[id] : 0.0;
  int    c = bad ? 1 : 0;
  for (int off = 32; off; off >>= 1) {
    v += __shfl_down(v, off);
    c += __shfl_down(c, off);
  }
  __shared__ double sv[4];
  __shared__ int    sc[4];
  int w = threadIdx.x >> 6, lane = threadIdx.x & 63;
  if (lane == 0) { sv[w] = v; sc[w] = c; }
  __syncthreads();
  if (threadIdx.x == 0) {
    double tv = sv[0]+sv[1]+sv[2]+sv[3];
    int    tc = sc[0]+sc[1]+sc[2]+sc[3];
    atomicAdd(sum, tv);
    atomicAdd(cnt, (unsigned long long)tc);
  }
}

// Stage 2b: belief map
__global__ __launch_bounds__(256) void bm_k(
    const float* __restrict__ xhat, const double* __restrict__ s32,
    const double* __restrict__ sum, const unsigned long long* __restrict__ cnt,
    float* __restrict__ bm)
{
  int id = blockIdx.x*256 + threadIdx.x;
  int b = id >> 18, rem = id & (IMGPIX-1);
  int oy = rem >> 9, ox = rem & 511;
  double ps = upsample_ps(s32, b, oy, ox);
  unsigned long long n = *cnt; if (n < 1) n = 1;
  float mean = (float)(*sum / (double)n);
  bm[id] = (ps < 0.5) ? mean : xhat[id];
}

// Stage 2c: separable 7x7 max — row pass
__global__ __launch_bounds__(512) void rowmax_k(
    const float* __restrict__ bm, float* __restrict__ rm)
{
  int id = blockIdx.x*512 + threadIdx.x;
  int x = id & 511;
  int base = id - x;
  int lo = max(x-3, 0), hi = min(x+3, 511);
  float m = bm[base + lo];
  for (int xx = lo+1; xx <= hi; ++xx) m = fmaxf(m, bm[base + xx]);
  rm[id] = m;
}

// Stage 2d: column max + key generation
__global__ __launch_bounds__(512) void keys_k(
    const float* __restrict__ bm, const float* __restrict__ rm,
    unsigned long long* __restrict__ keys)
{
  int id = blockIdx.x*512 + threadIdx.x;
  int rem = id & (IMGPIX-1);
  int x = rem & 511, y = rem >> 9;
  int imgbase = id - rem;
  int lo = max(y-3, 0), hi = min(y+3, 511);
  float mp = rm[imgbase + (lo<<9) + x];
  for (int yy = lo+1; yy <= hi; ++yy) mp = fmaxf(mp, rm[imgbase + (yy<<9) + x]);
  float v = bm[id];
  bool cand = (v == mp) && (v > NMS_THR);
  unsigned int inv = (unsigned int)((IMGPIX-1) - rem);
  unsigned long long key = cand
      ? ((((unsigned long long)__float_as_uint(v)) << 18) | inv)
      : (unsigned long long)inv;
  keys[id] = key;
}

// ---------------------------------------------------------------------------
// Stage 2e: exact per-image top-512 (radix-select on 50-bit keys) + sort
// ---------------------------------------------------------------------------
__global__ __launch_bounds__(1024) void select_k(
    const unsigned long long* __restrict__ keys,
    float* __restrict__ out, int* __restrict__ props)
{
  __shared__ unsigned int hA[2048], hB[2048];
  __shared__ unsigned long long sel[512];
  __shared__ unsigned int s_cnt;
  __shared__ unsigned long long s_pfx;
  __shared__ unsigned int s_R;
  const int b = blockIdx.x, tid = threadIdx.x;
  const int lane = tid & 63;
  const unsigned long long* kb = keys + ((size_t)b << 18);

  if (tid == 0) { s_pfx = 0ull; s_R = KSEL; s_cnt = 0; }
  __syncthreads();

  for (int pass = 0; pass < 5; ++pass) {
    const int shift = (pass < 4) ? (39 - pass*11) : 0;
    const int width = (pass < 4) ? 11 : 6;
    const unsigned int mask = (1u << width) - 1u;
    for (int i = tid; i < 2048; i += 1024) hA[i] = 0;
    __syncthreads();
    const unsigned long long pfx = s_pfx;
    const unsigned int R = s_R;
    // Histogram with wave-ballot aggregation (survives 1e5-way value ties).
    for (int i = 0; i < 256; ++i) {
      unsigned long long k = kb[tid + (i << 10)];
      bool pred = ((k >> (shift + width)) == pfx);
      int bin = (int)((unsigned int)(k >> shift) & mask);
      unsigned long long active = __ballot(pred);
      while (active) {
        int src = __ffsll((long long)active) - 1;
        int bsel = __shfl(bin, src);
        unsigned long long match = __ballot(bin == bsel) & active;
        if (lane == src) atomicAdd(&hA[bsel], (unsigned int)__popcll(match));
        active &= ~match;
      }
    }
    __syncthreads();
    // Inclusive suffix-sum (Hillis-Steele, ping-pong)
    unsigned int* srcp = hA; unsigned int* dstp = hB;
    for (int d = 1; d < 2048; d <<= 1) {
      for (int i = tid; i < 2048; i += 1024) {
        unsigned int v = srcp[i];
        if (i + d < 2048) v += srcp[i + d];
        dstp[i] = v;
      }
      __syncthreads();
      unsigned int* tmp = srcp; srcp = dstp; dstp = tmp;
    }
    // Find cut digit: largest i with suffix[i] >= R (suffix monotone)
    for (int i = tid; i < 2048; i += 1024) {
      unsigned int sfx = srcp[i];
      unsigned int nxt = (i + 1 < 2048) ? srcp[i + 1] : 0u;
      if (sfx >= R && nxt < R) {
        s_pfx = (pfx << width) | (unsigned long long)(unsigned int)i;
        s_R = R - nxt;
      }
    }
    __syncthreads();
  }

  const unsigned long long cutkey = s_pfx;  // rank-512 key (keys are distinct)
  for (int i = 0; i < 256; ++i) {
    unsigned long long k = kb[tid + (i << 10)];
    if (k >= cutkey) {
      unsigned int pos = atomicAdd(&s_cnt, 1u);
      if (pos < 512) sel[pos] = k;
    }
  }
  __syncthreads();

  // Bitonic sort, descending (value desc, index asc via inverted-index bits)
  for (int size = 2; size <= 512; size <<= 1) {
    for (int stride = size >> 1; stride > 0; stride >>= 1) {
      int i = tid;
      if (i < 512) {
        int j = i ^ stride;
        if (j > i) {
          unsigned long long a = sel[i], c = sel[j];
          bool up = ((i & size) == 0);
          if (up ? (a < c) : (a > c)) { sel[i] = c; sel[j] = a; }
        }
      }
      __syncthreads();
    }
  }

  for (int j = tid; j < 512; j += 1024) {
    unsigned long long k = sel[j];
    unsigned int fbits = (unsigned int)(k >> 18);
    int idx = (IMGPIX-1) - (int)(k & 0x3FFFFull);
    int y = idx >> 9, x = idx & 511;
    float val = fbits ? __uint_as_float(fbits) : -INFINITY;
    int slot = (b << 9) + j;
    out[12288 + slot]       = val;              // top_s
    out[8192 + slot*2 + 0]  = (float)x;         // coords x
    out[8192 + slot*2 + 1]  = (float)y;         // coords y
    out[14336 + slot]       = (val > NMS_THR) ? 1.0f : 0.0f;  // valid
    props[slot*2 + 0] = x;
    props[slot*2 + 1] = y;
  }
}

// ---------------------------------------------------------------------------
// Stage 3+4: ROI-align + 3x3 conv head, one block (512 thr) per proposal.
// LDS: single padded f32 buffer A[256][7][9] (x-padded, 63 f/ch = 63 KB),
// layer outputs live in registers (thread = (oc, row-half)) and are written
// back in place after a barrier.
// ---------------------------------------------------------------------------
template<int IY0, int NY, int IC>
__device__ __forceinline__ void conv_layer_acc(const float* __restrict__ wbase,
                                               const float* __restrict__ A,
                                               float* __restrict__ acc)
{
#pragma unroll
  for (int j = 0; j < NY*7; ++j) acc[j] = 0.f;
  for (int ic = 0; ic < IC; ++ic) {
    const float* __restrict__ wp = wbase + ic*9;
    float w[9];
#pragma unroll
    for (int q = 0; q < 9; ++q) w[q] = wp[q];
    const float* __restrict__ Ar = A + ic*63;
    float rows[NY+2][9];
#pragma unroll
    for (int r = 0; r < NY+2; ++r) {
      const int y = IY0 - 1 + r;
#pragma unroll
      for (int xs = 0; xs < 9; ++xs)
        rows[r][xs] = (y >= 0 && y <= 6) ? Ar[y*9 + xs] : 0.f;
    }
#pragma unroll
    for (int ry = 0; ry < NY; ++ry) {
#pragma unroll
      for (int ix = 0; ix < 7; ++ix) {
        float s = acc[ry*7 + ix];
#pragma unroll
        for (int ky = 0; ky < 3; ++ky)
#pragma unroll
          for (int kx = 0; kx < 3; ++kx)
            s = fmaf(w[ky*3+kx], rows[ry+ky][ix+kx], s);
        acc[ry*7 + ix] = s;
      }
    }
  }
}

template<int IY0, int NY>
__device__ __forceinline__ void writeback(float* __restrict__ A, int oc,
                                          float bias, const float* __restrict__ acc)
{
#pragma unroll
  for (int ry = 0; ry < NY; ++ry)
#pragma unroll
    for (int ix = 0; ix < 7; ++ix) {
      float v = acc[ry*7+ix] + bias;
      A[oc*63 + (IY0+ry)*9 + ix + 1] = LRELU_F(v);
    }
}

__global__ __launch_bounds__(512) void head_k(
    const float* __restrict__ fup, const int* __restrict__ props,
    const float* __restrict__ qw1, const float* __restrict__ qb1,
    const float* __restrict__ qw2, const float* __restrict__ qb2,
    const float* __restrict__ qw3, const float* __restrict__ qb3,
    const float* __restrict__ qfcw, const float* __restrict__ qfcb,
    float* __restrict__ out)
{
  __shared__ float A[256*63];   // 63 KB
  const int p = blockIdx.x;
  const int b = p >> 9;
  const int tid = threadIdx.x;
  const int oc = tid & 255;
  const int half = tid >> 8;    // wave-uniform (256-aligned)

  for (int i = tid; i < 256*63; i += 512) A[i] = 0.f;
  __syncthreads();

  // ROI-align (exact reference arithmetic)
  const int cx = props[2*p], cy = props[2*p+1];
  const float step = (float)(10.0/7.0);
  for (int it = tid; it < CUP*49; it += 512) {
    int c = it / 49, bin = it - c*49;
    int iy = bin / 7, ix = bin - iy*7;
    float fy = ((float)cy - 5.0f) + ((float)iy + 0.5f)*step;
    float fx = ((float)cx - 5.0f) + ((float)ix + 0.5f)*step;
    float y0f = floorf(fy), x0f = floorf(fx);
    float wy = fy - y0f,    wx = fx - x0f;
    int y0 = (int)y0f, x0 = (int)x0f;
    int y0i = min(max(y0,   0), 511), y1i = min(max(y0+1, 0), 511);
    int x0i = min(max(x0,   0), 511), x1i = min(max(x0+1, 0), 511);
    const float* f = fup + ((size_t)(b*CUP + c) << 18);
    float v00 = f[(y0i<<9)+x0i], v01 = f[(y0i<<9)+x1i];
    float v10 = f[(y1i<<9)+x0i], v11 = f[(y1i<<9)+x1i];
    float v = v00*(1.f-wy)*(1.f-wx) + v01*(1.f-wy)*wx
            + v10*wy*(1.f-wx)       + v11*wy*wx;
    A[c*63 + iy*9 + ix + 1] = v;
  }
  __syncthreads();

  float acc[28];

  // conv1: 64 -> 256
  if (half == 0) conv_layer_acc<0,4,64>(qw1 + oc*64*9, A, acc);
  else           conv_layer_acc<4,3,64>(qw1 + oc*64*9, A, acc);
  __syncthreads();
  {
    float bv = qb1[oc];
    if (half == 0) writeback<0,4>(A, oc, bv, acc);
    else           writeback<4,3>(A, oc, bv, acc);
  }
  __syncthreads();

  // conv2: 256 -> 256
  if (half == 0) conv_layer_acc<0,4,256>(qw2 + oc*256*9, A, acc);
  else           conv_layer_acc<4,3,256>(qw2 + oc*256*9, A, acc);
  __syncthreads();
  {
    float bv = qb2[oc];
    if (half == 0) writeback<0,4>(A, oc, bv, acc);
    else           writeback<4,3>(A, oc, bv, acc);
  }
  __syncthreads();

  // conv3: 256 -> 256 (stays in registers) + leaky + spatial max
  if (half == 0) conv_layer_acc<0,4,256>(qw3 + oc*256*9, A, acc);
  else           conv_layer_acc<4,3,256>(qw3 + oc*256*9, A, acc);
  __syncthreads();   // all LDS reads of conv3 done; A becomes scratch
  {
    float bv = qb3[oc];
    float m = -3.4e38f;
    const int nb = (half == 0) ? 28 : 21;
    for (int j = 0; j < nb; ++j) {
      float v = acc[j] + bv;
      m = fmaxf(m, LRELU_F(v));
    }
    A[half*256 + oc] = m;
  }
  __syncthreads();
  if (half == 0) {
    float h = fmaxf(A[oc], A[256 + oc]);
#pragma unroll
    for (int j = 0; j < 4; ++j)
      A[j*256 + oc] = h * qfcw[j*256 + oc];
  }
  __syncthreads();
  // tree-reduce each 256-segment
  {
    int j = tid >> 7, o = tid & 127;
    A[j*256+o] += A[j*256+o+128]; __syncthreads();
    if (o < 64) A[j*256+o] += A[j*256+o+64];  __syncthreads();
    if (o < 32) A[j*256+o] += A[j*256+o+32];  __syncthreads();
    if (o < 16) A[j*256+o] += A[j*256+o+16];  __syncthreads();
    if (o <  8) A[j*256+o] += A[j*256+o+8];   __syncthreads();
    if (o <  4) A[j*256+o] += A[j*256+o+4];   __syncthreads();
    if (o <  2) A[j*256+o] += A[j*256+o+2];   __syncthreads();
    if (o <  1) A[j*256+o] += A[j*256+o+1];   __syncthreads();
    if (o == 0) out[p*4 + j] = A[j*256] + qfcb[j];
  }
}

// ---------------------------------------------------------------------------
extern "C" void kernel_launch(void* const* d_in, const int* in_sizes, int n_in,
                              void* d_out, int out_size, void* d_ws, size_t ws_size,
                              hipStream_t stream)
{
  (void)in_sizes; (void)n_in; (void)out_size; (void)ws_size;
  const float* xhat  = (const float*)d_in[0];
  const float* fdown = (const float*)d_in[1];
  const float* fup   = (const float*)d_in[2];
  const float* pw1   = (const float*)d_in[3];
  const float* pb1   = (const float*)d_in[4];
  const float* pw2   = (const float*)d_in[5];
  const float* pb2   = (const float*)d_in[6];
  const float* pw3   = (const float*)d_in[7];
  const float* pb3   = (const float*)d_in[8];
  const float* pfcw  = (const float*)d_in[9];
  const float* pfcb  = (const float*)d_in[10];
  const float* qw1   = (const float*)d_in[11];
  const float* qb1   = (const float*)d_in[12];
  const float* qw2   = (const float*)d_in[13];
  const float* qb2   = (const float*)d_in[14];
  const float* qw3   = (const float*)d_in[15];
  const float* qb3   = (const float*)d_in[16];
  const float* qfcw  = (const float*)d_in[17];
  const float* qfcb  = (const float*)d_in[18];

  char* ws = (char*)d_ws;
  double*             s32  = (double*)(ws + OFF_S32);
  double*             sum  = (double*)(ws + OFF_SUM);
  unsigned long long* cnt  = (unsigned long long*)(ws + OFF_CNT);
  float*              bm   = (float*)(ws + OFF_BM);
  float*              rm   = (float*)(ws + OFF_RM);
  unsigned long long* keys = (unsigned long long*)(ws + OFF_KEYS);
  int*                props= (int*)(ws + OFF_PROPS);
  float*              out  = (float*)d_out;

  hipMemsetAsync(ws + OFF_SUM, 0, 16, stream);
  patch_k <<<256, 256, 0, stream>>>(fdown, pw1,pb1, pw2,pb2, pw3,pb3, pfcw,pfcb, s32);
  mean_k  <<<4096, 256, 0, stream>>>(xhat, s32, sum, cnt);
  bm_k    <<<4096, 256, 0, stream>>>(xhat, s32, sum, cnt, bm);
  rowmax_k<<<2048, 512, 0, stream>>>(bm, rm);
  keys_k  <<<2048, 512, 0, stream>>>(bm, rm, keys);
  select_k<<<BB, 1024, 0, stream>>>(keys, out, props);
  head_k  <<<NPROP, 512, 0, stream>>>(fup, props, qw1,qb1, qw2,qb2, qw3,qb3, qfcw,qfcb, out);
}

// Round 2
// 1435.893 us; speedup vs baseline: 3.5153x; 3.5153x over previous
//
#include <hip/hip_runtime.h>
#include <math.h>

typedef _Float16 half_t;
typedef half_t half8 __attribute__((ext_vector_type(8)));
typedef half_t half4 __attribute__((ext_vector_type(4)));
typedef float  f32x4 __attribute__((ext_vector_type(4)));

// Problem constants
#define BB 4
#define HH 512
#define WW 512
#define IMGPIX (HH*WW)        // 262144
#define NPIX (BB*IMGPIX)      // 1048576
#define KSEL 512
#define NPROP (BB*KSEL)       // 2048
#define CUP 64
#define NMS_THR 0.2f

// Workspace layout (bytes)
#define OFF_S32   0                       // double[4096]  = 32768
#define OFF_SUM   32768                   // double
#define OFF_CNT   32776                   // ull
#define OFF_BM    33280                   // float[1048576] = 4 MB
#define OFF_RM    (OFF_BM + 4194304)
#define OFF_KEYS  (OFF_RM + 4194304)      // u64[1048576] = 8 MB
#define OFF_PROPS (OFF_KEYS + 8388608)    // int[4096]
#define OFF_W1    (OFF_PROPS + 16384)     // half[9*2*256*32]  = 294912 B
#define OFF_W2    (OFF_W1 + 294912)       // half[9*8*256*32]  = 1179648 B
#define OFF_W3    (OFF_W2 + 1179648)

#define LRELU_F(x) ((x) > 0.0f ? (x) : 0.1f*(x))

// ---------------------------------------------------------------------------
// Stage 1: per-pixel patch MLP (f64 for numerical fidelity), 16 px per block
// ---------------------------------------------------------------------------
__global__ __launch_bounds__(256) void patch_k(
    const float* __restrict__ fdown,
    const float* __restrict__ pw1, const float* __restrict__ pb1,
    const float* __restrict__ pw2, const float* __restrict__ pb2,
    const float* __restrict__ pw3, const float* __restrict__ pb3,
    const float* __restrict__ pfcw, const float* __restrict__ pfcb,
    double* __restrict__ s32)
{
  __shared__ double xb[16][256];
  const int t = threadIdx.x;
  const int base_px = blockIdx.x * 16;
#pragma unroll
  for (int p = 0; p < 16; ++p) {
    int px = base_px + p;
    int b = px >> 10, rem = px & 1023;
    xb[p][t] = (double)fdown[(size_t)(b*256 + t)*1024 + rem];
  }
  __syncthreads();
  const float* Ws[3] = {pw1, pw2, pw3};
  const float* Bs[3] = {pb1, pb2, pb3};
  for (int L = 0; L < 3; ++L) {
    double acc[16];
    double bias = (double)Bs[L][t];
#pragma unroll
    for (int p = 0; p < 16; ++p) acc[p] = bias;
    const float* wrow = Ws[L] + t*256;
    for (int c = 0; c < 256; ++c) {
      double wv = (double)wrow[c];
#pragma unroll
      for (int p = 0; p < 16; ++p) acc[p] += wv * xb[p][c];
    }
    __syncthreads();
#pragma unroll
    for (int p = 0; p < 16; ++p)
      xb[p][t] = acc[p] > 0.0 ? acc[p] : 0.1*acc[p];
    __syncthreads();
  }
  if (t < 16) {
    double l0 = (double)pfcb[0], l1 = (double)pfcb[1];
    for (int c = 0; c < 256; ++c) {
      double xv = xb[t][c];
      l0 += (double)pfcw[c]       * xv;
      l1 += (double)pfcw[256 + c] * xv;
    }
    double m  = fmax(l0, l1);
    double e0 = exp(l0 - m), e1 = exp(l1 - m);
    s32[base_px + t] = e1 / (e0 + e1);
  }
}

// Bilinear upsample 32->512 (align_corners=False), matches jax.image.resize.
__device__ __forceinline__ double upsample_ps(const double* __restrict__ s32,
                                              int b, int oy, int ox)
{
  double sy = (oy + 0.5)*0.0625 - 0.5;
  double sx = (ox + 0.5)*0.0625 - 0.5;
  double fy = floor(sy), fx = floor(sx);
  double wy = sy - fy,   wx = sx - fx;
  int y0 = (int)fy, x0 = (int)fx;
  int y0i = min(max(y0,   0), 31), y1i = min(max(y0+1, 0), 31);
  int x0i = min(max(x0,   0), 31), x1i = min(max(x0+1, 0), 31);
  const double* s = s32 + b*1024;
  double v00 = s[y0i*32+x0i], v01 = s[y0i*32+x1i];
  double v10 = s[y1i*32+x0i], v11 = s[y1i*32+x1i];
  return v00*(1.0-wy)*(1.0-wx) + v01*(1.0-wy)*wx
       + v10*wy*(1.0-wx)       + v11*wy*wx;
}

// ---------------------------------------------------------------------------
// Stage 2a: global bad-pixel sum/count (f64 accumulation)
// ---------------------------------------------------------------------------
__global__ __launch_bounds__(256) void mean_k(
    const float* __restrict__ xhat, const double* __restrict__ s32,
    double* __restrict__ sum, unsigned long long* __restrict__ cnt)
{
  int id = blockIdx.x*256 + threadIdx.x;
  int b = id >> 18, rem = id & (IMGPIX-1);
  int oy = rem >> 9, ox = rem & 511;
  double ps = upsample_ps(s32, b, oy, ox);
  bool bad = ps < 0.5;
  double v = bad ? (double)xhat[id] : 0.0;
  int    c = bad ? 1 : 0;
  for (int off = 32; off; off >>= 1) {
    v += __shfl_down(v, off);
    c += __shfl_down(c, off);
  }
  __shared__ double sv[4];
  __shared__ int    sc[4];
  int w = threadIdx.x >> 6, lane = threadIdx.x & 63;
  if (lane == 0) { sv[w] = v; sc[w] = c; }
  __syncthreads();
  if (threadIdx.x == 0) {
    double tv = sv[0]+sv[1]+sv[2]+sv[3];
    int    tc = sc[0]+sc[1]+sc[2]+sc[3];
    atomicAdd(sum, tv);
    atomicAdd(cnt, (unsigned long long)tc);
  }
}

// Stage 2b: belief map
__global__ __launch_bounds__(256) void bm_k(
    const float* __restrict__ xhat, const double* __restrict__ s32,
    const double* __restrict__ sum, const unsigned long long* __restrict__ cnt,
    float* __restrict__ bm)
{
  int id = blockIdx.x*256 + threadIdx.x;
  int b = id >> 18, rem = id & (IMGPIX-1);
  int oy = rem >> 9, ox = rem & 511;
  double ps = upsample_ps(s32, b, oy, ox);
  unsigned long long n = *cnt; if (n < 1) n = 1;
  float mean = (float)(*sum / (double)n);
  bm[id] = (ps < 0.5) ? mean : xhat[id];
}

// Stage 2c: separable 7x7 max — row pass
__global__ __launch_bounds__(512) void rowmax_k(
    const float* __restrict__ bm, float* __restrict__ rm)
{
  int id = blockIdx.x*512 + threadIdx.x;
  int x = id & 511;
  int base = id - x;
  int lo = max(x-3, 0), hi = min(x+3, 511);
  float m = bm[base + lo];
  for (int xx = lo+1; xx <= hi; ++xx) m = fmaxf(m, bm[base + xx]);
  rm[id] = m;
}

// Stage 2d: column max + key generation
__global__ __launch_bounds__(512) void keys_k(
    const float* __restrict__ bm, const float* __restrict__ rm,
    unsigned long long* __restrict__ keys)
{
  int id = blockIdx.x*512 + threadIdx.x;
  int rem = id & (IMGPIX-1);
  int x = rem & 511, y = rem >> 9;
  int imgbase = id - rem;
  int lo = max(y-3, 0), hi = min(y+3, 511);
  float mp = rm[imgbase + (lo<<9) + x];
  for (int yy = lo+1; yy <= hi; ++yy) mp = fmaxf(mp, rm[imgbase + (yy<<9) + x]);
  float v = bm[id];
  bool cand = (v == mp) && (v > NMS_THR);
  unsigned int inv = (unsigned int)((IMGPIX-1) - rem);
  unsigned long long key = cand
      ? ((((unsigned long long)__float_as_uint(v)) << 18) | inv)
      : (unsigned long long)inv;
  keys[id] = key;
}

// ---------------------------------------------------------------------------
// Stage 2e: exact per-image top-512 (radix-select on 50-bit keys) + sort
// ---------------------------------------------------------------------------
__global__ __launch_bounds__(1024) void select_k(
    const unsigned long long* __restrict__ keys,
    float* __restrict__ out, int* __restrict__ props)
{
  __shared__ unsigned int hA[2048], hB[2048];
  __shared__ unsigned long long sel[512];
  __shared__ unsigned int s_cnt;
  __shared__ unsigned long long s_pfx;
  __shared__ unsigned int s_R;
  const int b = blockIdx.x, tid = threadIdx.x;
  const int lane = tid & 63;
  const unsigned long long* kb = keys + ((size_t)b << 18);

  if (tid == 0) { s_pfx = 0ull; s_R = KSEL; s_cnt = 0; }
  __syncthreads();

  for (int pass = 0; pass < 5; ++pass) {
    const int shift = (pass < 4) ? (39 - pass*11) : 0;
    const int width = (pass < 4) ? 11 : 6;
    const unsigned int mask = (1u << width) - 1u;
    for (int i = tid; i < 2048; i += 1024) hA[i] = 0;
    __syncthreads();
    const unsigned long long pfx = s_pfx;
    const unsigned int R = s_R;
    for (int i = 0; i < 256; ++i) {
      unsigned long long k = kb[tid + (i << 10)];
      bool pred = ((k >> (shift + width)) == pfx);
      int bin = (int)((unsigned int)(k >> shift) & mask);
      unsigned long long active = __ballot(pred);
      while (active) {
        int src = __ffsll((long long)active) - 1;
        int bsel = __shfl(bin, src);
        unsigned long long match = __ballot(bin == bsel) & active;
        if (lane == src) atomicAdd(&hA[bsel], (unsigned int)__popcll(match));
        active &= ~match;
      }
    }
    __syncthreads();
    unsigned int* srcp = hA; unsigned int* dstp = hB;
    for (int d = 1; d < 2048; d <<= 1) {
      for (int i = tid; i < 2048; i += 1024) {
        unsigned int v = srcp[i];
        if (i + d < 2048) v += srcp[i + d];
        dstp[i] = v;
      }
      __syncthreads();
      unsigned int* tmp = srcp; srcp = dstp; dstp = tmp;
    }
    for (int i = tid; i < 2048; i += 1024) {
      unsigned int sfx = srcp[i];
      unsigned int nxt = (i + 1 < 2048) ? srcp[i + 1] : 0u;
      if (sfx >= R && nxt < R) {
        s_pfx = (pfx << width) | (unsigned long long)(unsigned int)i;
        s_R = R - nxt;
      }
    }
    __syncthreads();
  }

  const unsigned long long cutkey = s_pfx;
  for (int i = 0; i < 256; ++i) {
    unsigned long long k = kb[tid + (i << 10)];
    if (k >= cutkey) {
      unsigned int pos = atomicAdd(&s_cnt, 1u);
      if (pos < 512) sel[pos] = k;
    }
  }
  __syncthreads();

  for (int size = 2; size <= 512; size <<= 1) {
    for (int stride = size >> 1; stride > 0; stride >>= 1) {
      int i = tid;
      if (i < 512) {
        int j = i ^ stride;
        if (j > i) {
          unsigned long long a = sel[i], c = sel[j];
          bool up = ((i & size) == 0);
          if (up ? (a < c) : (a > c)) { sel[i] = c; sel[j] = a; }
        }
      }
      __syncthreads();
    }
  }

  for (int j = tid; j < 512; j += 1024) {
    unsigned long long k = sel[j];
    unsigned int fbits = (unsigned int)(k >> 18);
    int idx = (IMGPIX-1) - (int)(k & 0x3FFFFull);
    int y = idx >> 9, x = idx & 511;
    float val = fbits ? __uint_as_float(fbits) : -INFINITY;
    int slot = (b << 9) + j;
    out[12288 + slot]       = val;
    out[8192 + slot*2 + 0]  = (float)x;
    out[8192 + slot*2 + 1]  = (float)y;
    out[14336 + slot]       = (val > NMS_THR) ? 1.0f : 0.0f;
    props[slot*2 + 0] = x;
    props[slot*2 + 1] = y;
  }
}

// ---------------------------------------------------------------------------
// Weight repack: qw[oc][ic][ky][kx] f32 -> [tap][kstep][oc][32] f16
// (fragment-contiguous: one 16x16x32 A-frag = 1 KB contiguous)
// ---------------------------------------------------------------------------
__global__ void repack_k(const float* __restrict__ src, half_t* __restrict__ dst,
                         int IC, int KS, int total)
{
  int idx = blockIdx.x*256 + threadIdx.x;
  if (idx >= total) return;
  int tap = idx % 9;
  int t   = idx / 9;
  int ic  = t % IC;
  int oc  = t / IC;
  int ks  = ic >> 5, kin = ic & 31;
  dst[((size_t)(tap*KS + ks)*256 + oc)*32 + kin] = (half_t)src[idx];
}

// ---------------------------------------------------------------------------
// Stage 3+4 (MFMA): per proposal-block GEMM-per-tap.
//   M = oc (256, 16 Mtiles), N = px (64, 4 Ntiles), K = ic.
//   A = W[tap][ks][oc][32] f16 from global (coalesced 1 KB frags)
//   B = X[px][ic] f16 in LDS (stride SA, 2-way bank alias only); row 64 == 0
//   Wave w owns Mtiles {2w,2w+1} x all 4 Ntiles (8 acc tiles).
// ---------------------------------------------------------------------------
#define SA2 264   // conv2/3 input stride (halves)
#define SA1 72    // conv1 input stride

template<int KS, int SA>
__device__ __forceinline__ void conv_mfma(const half_t* __restrict__ Wl,
                                          const half_t* __restrict__ Xin,
                                          int w, int quad, int c15,
                                          f32x4 acc[2][4])
{
#pragma unroll
  for (int mi = 0; mi < 2; ++mi)
#pragma unroll
    for (int nt = 0; nt < 4; ++nt) acc[mi][nt] = (f32x4){0.f, 0.f, 0.f, 0.f};

  const int oc0 = (w*2)*16 + c15;
  for (int tap = 0; tap < 9; ++tap) {
    const int dy = tap/3 - 1, dx = tap%3 - 1;
    int xoff[4];
#pragma unroll
    for (int nt = 0; nt < 4; ++nt) {
      int px = nt*16 + c15;
      int y = px/7, x = px - y*7;
      int yy = y + dy, xx = x + dx;
      bool valid = (px < 49) & (yy >= 0) & (yy < 7) & (xx >= 0) & (xx < 7);
      int spx = valid ? (yy*7 + xx) : 64;
      xoff[nt] = spx*SA + quad*8;
    }
    const half_t* wbase = Wl + ((size_t)(tap*KS)*256 + oc0)*32 + quad*8;
#pragma unroll 2
    for (int ks = 0; ks < KS; ++ks) {
      half8 bfr[4];
#pragma unroll
      for (int nt = 0; nt < 4; ++nt)
        bfr[nt] = *(const half8*)(Xin + xoff[nt] + ks*32);
      half8 afr[2];
#pragma unroll
      for (int mi = 0; mi < 2; ++mi)
        afr[mi] = *(const half8*)(wbase + (size_t)(ks*256 + mi*16)*32);
#pragma unroll
      for (int mi = 0; mi < 2; ++mi)
#pragma unroll
        for (int nt = 0; nt < 4; ++nt)
          acc[mi][nt] = __builtin_amdgcn_mfma_f32_16x16x32_f16(
              afr[mi], bfr[nt], acc[mi][nt], 0, 0, 0);
    }
  }
}

__device__ __forceinline__ void store_layer(half_t* __restrict__ Xo,
                                            const float* __restrict__ bias,
                                            int w, int quad, int c15,
                                            f32x4 acc[2][4])
{
#pragma unroll
  for (int mi = 0; mi < 2; ++mi) {
    int ocb = (w*2 + mi)*16 + quad*4;
#pragma unroll
    for (int nt = 0; nt < 4; ++nt) {
      int px = nt*16 + c15;
      half4 h;
#pragma unroll
      for (int r = 0; r < 4; ++r) {
        float v = acc[mi][nt][r] + bias[ocb + r];
        h[r] = (half_t)LRELU_F(v);
      }
      *(half4*)(Xo + px*SA2 + ocb) = h;
    }
  }
}

__global__ __launch_bounds__(512) void head_k(
    const float* __restrict__ fup, const int* __restrict__ props,
    const half_t* __restrict__ W1, const half_t* __restrict__ W2,
    const half_t* __restrict__ W3,
    const float* __restrict__ qb1, const float* __restrict__ qb2,
    const float* __restrict__ qb3,
    const float* __restrict__ qfcw, const float* __restrict__ qfcb,
    float* __restrict__ out)
{
  __shared__ half_t X2[65*SA2];   // 34320 B, rows 0..63 = activations, row 64 = 0
  __shared__ half_t X1[65*SA1];   // 9360 B
  __shared__ float  S[5*256];     // H[256] + P[4][256]

  const int p = blockIdx.x, b = p >> 9, tid = threadIdx.x;
  const int w = tid >> 6, lane = tid & 63;
  const int quad = lane >> 4, c15 = lane & 15;

  // zero pad rows: X1 rows 49..64, X2 row 64
  for (int i = tid; i < 16*SA1; i += 512) X1[49*SA1 + i] = (half_t)0.f;
  for (int i = tid; i < SA2;    i += 512) X2[64*SA2 + i] = (half_t)0.f;

  // ROI-align -> X1[px][c] (exact reference arithmetic, then f16 quantize)
  const int cx = props[2*p], cy = props[2*p+1];
  const float step = (float)(10.0/7.0);
  for (int it = tid; it < CUP*49; it += 512) {
    int c = it / 49, bin = it - c*49;
    int iy = bin / 7, ix = bin - iy*7;
    float fy = ((float)cy - 5.0f) + ((float)iy + 0.5f)*step;
    float fx = ((float)cx - 5.0f) + ((float)ix + 0.5f)*step;
    float y0f = floorf(fy), x0f = floorf(fx);
    float wy = fy - y0f,    wx = fx - x0f;
    int y0 = (int)y0f, x0 = (int)x0f;
    int y0i = min(max(y0,   0), 511), y1i = min(max(y0+1, 0), 511);
    int x0i = min(max(x0,   0), 511), x1i = min(max(x0+1, 0), 511);
    const float* f = fup + ((size_t)(b*CUP + c) << 18);
    float v00 = f[(y0i<<9)+x0i], v01 = f[(y0i<<9)+x1i];
    float v10 = f[(y1i<<9)+x0i], v11 = f[(y1i<<9)+x1i];
    float v = v00*(1.f-wy)*(1.f-wx) + v01*(1.f-wy)*wx
            + v10*wy*(1.f-wx)       + v11*wy*wx;
    X1[(iy*7 + ix)*SA1 + c] = (half_t)v;
  }
  __syncthreads();

  f32x4 acc[2][4];

  // conv1: ic=64 (KS=2)
  conv_mfma<2, SA1>(W1, X1, w, quad, c15, acc);
  __syncthreads();
  store_layer(X2, qb1, w, quad, c15, acc);
  __syncthreads();

  // conv2: ic=256 (KS=8), in-place
  conv_mfma<8, SA2>(W2, X2, w, quad, c15, acc);
  __syncthreads();
  store_layer(X2, qb2, w, quad, c15, acc);
  __syncthreads();

  // conv3: ic=256 -> bias+leaky+spatial max (registers only)
  conv_mfma<8, SA2>(W3, X2, w, quad, c15, acc);
#pragma unroll
  for (int mi = 0; mi < 2; ++mi)
#pragma unroll
    for (int r = 0; r < 4; ++r) {
      int oc = (w*2 + mi)*16 + quad*4 + r;
      float bv = qb3[oc];
      float m = -3.4e38f;
#pragma unroll
      for (int nt = 0; nt < 4; ++nt) {
        int px = nt*16 + c15;
        if (px < 49) {
          float v = acc[mi][nt][r] + bv;
          m = fmaxf(m, LRELU_F(v));
        }
      }
#pragma unroll
      for (int d = 1; d < 16; d <<= 1) m = fmaxf(m, __shfl_xor(m, d));
      if (c15 == 0) S[oc] = m;
    }
  __syncthreads();

  // FC 256 -> 4
  if (tid < 256) {
    float h = S[tid];
#pragma unroll
    for (int j = 0; j < 4; ++j) S[256 + j*256 + tid] = h * qfcw[j*256 + tid];
  }
  __syncthreads();
  {
    float* P = S + 256;
    int j = tid >> 7, o = tid & 127;
    P[j*256+o] += P[j*256+o+128]; __syncthreads();
    if (o < 64) P[j*256+o] += P[j*256+o+64];  __syncthreads();
    if (o < 32) P[j*256+o] += P[j*256+o+32];  __syncthreads();
    if (o < 16) P[j*256+o] += P[j*256+o+16];  __syncthreads();
    if (o <  8) P[j*256+o] += P[j*256+o+8];   __syncthreads();
    if (o <  4) P[j*256+o] += P[j*256+o+4];   __syncthreads();
    if (o <  2) P[j*256+o] += P[j*256+o+2];   __syncthreads();
    if (o <  1) P[j*256+o] += P[j*256+o+1];   __syncthreads();
    if (o == 0) out[p*4 + j] = P[j*256] + qfcb[j];
  }
}

// ---------------------------------------------------------------------------
extern "C" void kernel_launch(void* const* d_in, const int* in_sizes, int n_in,
                              void* d_out, int out_size, void* d_ws, size_t ws_size,
                              hipStream_t stream)
{
  (void)in_sizes; (void)n_in; (void)out_size; (void)ws_size;
  const float* xhat  = (const float*)d_in[0];
  const float* fdown = (const float*)d_in[1];
  const float* fup   = (const float*)d_in[2];
  const float* pw1   = (const float*)d_in[3];
  const float* pb1   = (const float*)d_in[4];
  const float* pw2   = (const float*)d_in[5];
  const float* pb2   = (const float*)d_in[6];
  const float* pw3   = (const float*)d_in[7];
  const float* pb3   = (const float*)d_in[8];
  const float* pfcw  = (const float*)d_in[9];
  const float* pfcb  = (const float*)d_in[10];
  const float* qw1   = (const float*)d_in[11];
  const float* qb1   = (const float*)d_in[12];
  const float* qw2   = (const float*)d_in[13];
  const float* qb2   = (const float*)d_in[14];
  const float* qw3   = (const float*)d_in[15];
  const float* qb3   = (const float*)d_in[16];
  const float* qfcw  = (const float*)d_in[17];
  const float* qfcb  = (const float*)d_in[18];

  char* ws = (char*)d_ws;
  double*             s32  = (double*)(ws + OFF_S32);
  double*             sum  = (double*)(ws + OFF_SUM);
  unsigned long long* cnt  = (unsigned long long*)(ws + OFF_CNT);
  float*              bm   = (float*)(ws + OFF_BM);
  float*              rm   = (float*)(ws + OFF_RM);
  unsigned long long* keys = (unsigned long long*)(ws + OFF_KEYS);
  int*                props= (int*)(ws + OFF_PROPS);
  half_t*             Wp1  = (half_t*)(ws + OFF_W1);
  half_t*             Wp2  = (half_t*)(ws + OFF_W2);
  half_t*             Wp3  = (half_t*)(ws + OFF_W3);
  float*              out  = (float*)d_out;

  hipMemsetAsync(ws + OFF_SUM, 0, 16, stream);

  const int tot1 = 256*64*9, tot2 = 256*256*9;
  repack_k<<<(tot1+255)/256, 256, 0, stream>>>(qw1, Wp1, 64, 2, tot1);
  repack_k<<<(tot2+255)/256, 256, 0, stream>>>(qw2, Wp2, 256, 8, tot2);
  repack_k<<<(tot2+255)/256, 256, 0, stream>>>(qw3, Wp3, 256, 8, tot2);

  patch_k <<<256, 256, 0, stream>>>(fdown, pw1,pb1, pw2,pb2, pw3,pb3, pfcw,pfcb, s32);
  mean_k  <<<4096, 256, 0, stream>>>(xhat, s32, sum, cnt);
  bm_k    <<<4096, 256, 0, stream>>>(xhat, s32, sum, cnt, bm);
  rowmax_k<<<2048, 512, 0, stream>>>(bm, rm);
  keys_k  <<<2048, 512, 0, stream>>>(bm, rm, keys);
  select_k<<<BB, 1024, 0, stream>>>(keys, out, props);
  head_k  <<<NPROP, 512, 0, stream>>>(fup, props, Wp1, Wp2, Wp3,
                                      qb1, qb2, qb3, qfcw, qfcb, out);
}